// Round 1
// baseline (802.886 us; speedup 1.0000x reference)
//
#include <hip/hip_runtime.h>
#include <hip/hip_fp16.h>

#define NB 8          // batch
#define NS 4096       // seq len
#define NH 2048       // hidden
#define NDH 64        // selector hidden
#define NK 256        // top-k
#define BK 32         // gemm k-chunk
#define MT 128        // tokens per block

// ---------------------------------------------------------------------------
// K1: logits = relu(hs @ w1 + b1) @ w2 + b2, fused with perturbed-output copy
// (out0 = fp16-rounded hs; selected rows zeroed later by K3's indices via K4).
// Tile: 128 tokens x 64 dh, 256 threads, thread tile 8 tokens x 4 dh.
// ---------------------------------------------------------------------------
__global__ __launch_bounds__(256) void k_sel_gemm(
    const float* __restrict__ hs, const float* __restrict__ w1,
    const float* __restrict__ b1, const float* __restrict__ w2,
    const float* __restrict__ b2, float* __restrict__ out0,
    float* __restrict__ logits)
{
    __shared__ float As[BK][MT + 4];   // +4 pad: keeps 16B alignment, breaks worst conflicts
    __shared__ float Ws[BK][NDH];

    const int tid = threadIdx.x;
    const int tx = tid & 15;           // dh group: columns tx*4 .. tx*4+3
    const int ty = tid >> 4;           // token group: tokens ty*8 .. ty*8+7
    const int tokenBase = blockIdx.x * MT;

    float acc[8][4];
#pragma unroll
    for (int i = 0; i < 8; ++i)
#pragma unroll
        for (int j = 0; j < 4; ++j) acc[i][j] = 0.0f;

    const float4 b1v = reinterpret_cast<const float4*>(b1)[tx];
    const float4 w2v = reinterpret_cast<const float4*>(w2)[tx];
    const float b2s = b2[0];

    for (int ko = 0; ko < NH; ko += BK) {
        // ---- stage A tile (128 tokens x 32 k) + fused fp16-rounded copy-out
#pragma unroll
        for (int r = 0; r < 4; ++r) {
            const int f  = r * 256 + tid;      // float4 index within tile (0..1023)
            const int tl = f >> 3;             // local token (0..127)
            const int k4 = (f & 7) * 4;        // k within chunk
            const long long gi = (long long)(tokenBase + tl) * NH + ko + k4;
            const float4 v = *reinterpret_cast<const float4*>(hs + gi);
            float4 o;
            o.x = __half2float(__float2half(v.x));
            o.y = __half2float(__float2half(v.y));
            o.z = __half2float(__float2half(v.z));
            o.w = __half2float(__float2half(v.w));
            *reinterpret_cast<float4*>(out0 + gi) = o;
            As[k4 + 0][tl] = v.x;
            As[k4 + 1][tl] = v.y;
            As[k4 + 2][tl] = v.z;
            As[k4 + 3][tl] = v.w;
        }
        // ---- stage W tile (32 k x 64 dh), layout already [k][dh]
#pragma unroll
        for (int r = 0; r < 2; ++r) {
            const int f  = r * 256 + tid;      // float4 index (0..511)
            const int kk = f >> 4;             // 16 float4 per row
            const int c  = (f & 15) * 4;
            *reinterpret_cast<float4*>(&Ws[kk][c]) =
                *reinterpret_cast<const float4*>(w1 + (long long)(ko + kk) * NDH + c);
        }
        __syncthreads();

#pragma unroll
        for (int kk = 0; kk < BK; ++kk) {
            const float4 a0 = *reinterpret_cast<const float4*>(&As[kk][ty * 8]);
            const float4 a1 = *reinterpret_cast<const float4*>(&As[kk][ty * 8 + 4]);
            const float4 wv = *reinterpret_cast<const float4*>(&Ws[kk][tx * 4]);
            const float a[8] = {a0.x, a0.y, a0.z, a0.w, a1.x, a1.y, a1.z, a1.w};
            const float w[4] = {wv.x, wv.y, wv.z, wv.w};
#pragma unroll
            for (int i = 0; i < 8; ++i)
#pragma unroll
                for (int j = 0; j < 4; ++j) acc[i][j] += a[i] * w[j];
        }
        __syncthreads();
    }

    // ---- epilogue: relu + dot with w2 (partial over this thread's 4 dh), then
    // reduce across tx (low 4 lane bits) and write logits.
    float s[8];
#pragma unroll
    for (int i = 0; i < 8; ++i) {
        float h0 = fmaxf(acc[i][0] + b1v.x, 0.0f);
        float h1 = fmaxf(acc[i][1] + b1v.y, 0.0f);
        float h2 = fmaxf(acc[i][2] + b1v.z, 0.0f);
        float h3 = fmaxf(acc[i][3] + b1v.w, 0.0f);
        s[i] = h0 * w2v.x + h1 * w2v.y + h2 * w2v.z + h3 * w2v.w;
    }
#pragma unroll
    for (int m = 1; m < 16; m <<= 1) {
#pragma unroll
        for (int i = 0; i < 8; ++i) s[i] += __shfl_xor(s[i], m, 64);
    }
    if (tx == 0) {
#pragma unroll
        for (int i = 0; i < 8; ++i)
            logits[tokenBase + ty * 8 + i] = s[i] + b2s;
    }
}

// ---------------------------------------------------------------------------
// K2: per-batch gumbel top-k via full bitonic sort in LDS (matches
// jax.lax.top_k order: value desc, tie -> lower index first), plus
// log_softmax gather mean. One block per batch, 1024 threads.
// ---------------------------------------------------------------------------
__global__ __launch_bounds__(1024) void k_topk(
    const float* __restrict__ logits, const float* __restrict__ noise,
    float* __restrict__ outIdx, float* __restrict__ outType,
    float* __restrict__ outLP, int* __restrict__ wsIdx)
{
    __shared__ float key[NS];
    __shared__ int   kidx[NS];
    __shared__ float rawl[NS];
    __shared__ float red[1024];

    const int b = blockIdx.x;
    const int tid = threadIdx.x;

    for (int e = tid; e < NS; e += 1024) {
        const float l = logits[b * NS + e];
        const float u = noise[b * NS + e];
        const float g = -logf(-logf(u));
        key[e]  = l + g;
        kidx[e] = e;
        rawl[e] = l;
    }
    __syncthreads();

    // bitonic sort, descending by (key, then ascending index)
    for (int k = 2; k <= NS; k <<= 1) {
        for (int j = k >> 1; j > 0; j >>= 1) {
            for (int t = tid; t < NS; t += 1024) {
                const int l2 = t ^ j;
                if (l2 > t) {
                    const float ka = key[t], kb = key[l2];
                    const int   ia = kidx[t], ib = kidx[l2];
                    const bool a_before = (ka > kb) || (ka == kb && ia < ib);
                    const bool up = ((t & k) == 0);
                    if (up != a_before) {
                        key[t] = kb;  key[l2] = ka;
                        kidx[t] = ib; kidx[l2] = ia;
                    }
                }
            }
            __syncthreads();
        }
    }

    // max of raw logits
    float lm = -INFINITY;
    for (int e = tid; e < NS; e += 1024) lm = fmaxf(lm, rawl[e]);
    red[tid] = lm;
    __syncthreads();
    for (int s2 = 512; s2 > 0; s2 >>= 1) {
        if (tid < s2) red[tid] = fmaxf(red[tid], red[tid + s2]);
        __syncthreads();
    }
    const float maxv = red[0];
    __syncthreads();

    // sum exp(l - max)
    float ls = 0.0f;
    for (int e = tid; e < NS; e += 1024) ls += expf(rawl[e] - maxv);
    red[tid] = ls;
    __syncthreads();
    for (int s2 = 512; s2 > 0; s2 >>= 1) {
        if (tid < s2) red[tid] += red[tid + s2];
        __syncthreads();
    }
    const float lse = logf(red[0]);
    __syncthreads();

    // emit top-K indices / types / log-prob contributions
    float contrib = 0.0f;
    if (tid < NK) {
        const int idx = kidx[tid];
        outIdx[b * NK + tid]  = (float)idx;
        outType[b * NK + tid] = 1.0f;     // FIXED_TYPE
        wsIdx[b * NK + tid]   = idx;
        contrib = rawl[idx] - maxv - lse;
    }
    red[tid] = contrib;
    __syncthreads();
    for (int s2 = 512; s2 > 0; s2 >>= 1) {
        if (tid < s2) red[tid] += red[tid + s2];
        __syncthreads();
    }
    if (tid == 0) outLP[b] = red[0] / (float)NK;
}

// ---------------------------------------------------------------------------
// K3: zero the selected rows of out0 (perturb value = TYPE_VALUES[1]*SCALE = 0)
// ---------------------------------------------------------------------------
__global__ __launch_bounds__(256) void k_zero_rows(
    const int* __restrict__ wsIdx, float* __restrict__ out0)
{
    const int blk = blockIdx.x;         // 0 .. NB*NK-1
    const int b = blk >> 8;
    const int r = blk & 255;
    const int row = wsIdx[b * NK + r];
    float4 z = make_float4(0.f, 0.f, 0.f, 0.f);
    float4* p = reinterpret_cast<float4*>(out0 + ((long long)(b * NS + row)) * NH);
    p[threadIdx.x]       = z;
    p[threadIdx.x + 256] = z;
}

extern "C" void kernel_launch(void* const* d_in, const int* in_sizes, int n_in,
                              void* d_out, int out_size, void* d_ws, size_t ws_size,
                              hipStream_t stream) {
    const float* hs    = (const float*)d_in[0];   // (B,S,H) fp32
    const float* noise = (const float*)d_in[1];   // (B,S)   fp32
    const float* w1    = (const float*)d_in[2];   // (H,DH)
    const float* b1    = (const float*)d_in[3];   // (DH,)
    const float* w2    = (const float*)d_in[4];   // (DH,1)
    const float* b2    = (const float*)d_in[5];   // (1,)

    float* out0    = (float*)d_out;                       // (B,S,H) perturbed (fp16-rounded vals)
    float* outIdx  = out0 + (long long)NB * NS * NH;      // (B,K) indices as float
    float* outType = outIdx + NB * NK;                    // (B,K) types as float
    float* outLP   = outType + NB * NK;                   // (B,)  log_prob

    float* logits = (float*)d_ws;                         // B*S floats
    int*   wsIdx  = (int*)d_ws + NB * NS;                 // B*K ints

    k_sel_gemm<<<(NB * NS) / MT, 256, 0, stream>>>(hs, w1, b1, w2, b2, out0, logits);
    k_topk<<<NB, 1024, 0, stream>>>(logits, noise, outIdx, outType, outLP, wsIdx);
    k_zero_rows<<<NB * NK, 256, 0, stream>>>(wsIdx, out0);
}

// Round 2
// 513.116 us; speedup vs baseline: 1.5647x; 1.5647x over previous
//
#include <hip/hip_runtime.h>
#include <hip/hip_fp16.h>

#define NB 8          // batch
#define NS 4096       // seq len
#define NH 2048       // hidden
#define NDH 64        // selector hidden dim
#define NK 256        // top-k
#define BK 32         // gemm k-chunk per LDS stage
#define MT 128        // tokens per block
#define KS 4          // split-K factor
#define KCH (NH / KS) // 512 k per block

// ---------------------------------------------------------------------------
// K1: partial = hs @ w1 over this block's k-chunk, fused with fp16-rounded
// copy of hs into out0. Grid = 256 token-tiles x KS k-chunks = 1024 blocks
// (4 blocks/CU, 8 waves/CU). 128 threads, thread tile 8 tok x 8 dh
// (1 B LDS / FMA). As stored [tok][k] (pitch 36 -> b128-aligned rows,
// conflict-free reads at token stride 16: bank = 4*ty + kk).
// ---------------------------------------------------------------------------
__global__ __launch_bounds__(128, 2) void k_sel_gemm(
    const float* __restrict__ hs, const float* __restrict__ w1,
    float* __restrict__ out0, float* __restrict__ part)
{
    __shared__ float As[MT][BK + 4];   // 36 floats/row
    __shared__ float Ws[BK][NDH];

    const int tid = threadIdx.x;
    const int tx = tid & 7;            // dh octet: dh = tx*8 .. tx*8+7
    const int ty = tid >> 3;           // token group: tokens ty + 16*t
    const int tile = blockIdx.x & 255;
    const int kc = blockIdx.x >> 8;
    const int tokenBase = tile * MT;
    const int kBase = kc * KCH;

    float acc[8][8];
#pragma unroll
    for (int t = 0; t < 8; ++t)
#pragma unroll
        for (int j = 0; j < 8; ++j) acc[t][j] = 0.0f;

    for (int ko = 0; ko < KCH; ko += BK) {
        // ---- stage A tile (128 tok x 32 k) + fused fp16-rounded copy-out
#pragma unroll
        for (int r = 0; r < 8; ++r) {
            const int f = r * 128 + tid;
            const int tok = f >> 3;
            const int k4 = (f & 7) * 4;
            const long long gi = (long long)(tokenBase + tok) * NH + kBase + ko + k4;
            const float4 v = *reinterpret_cast<const float4*>(hs + gi);
            float4 o;
            o.x = __half2float(__float2half(v.x));
            o.y = __half2float(__float2half(v.y));
            o.z = __half2float(__float2half(v.z));
            o.w = __half2float(__float2half(v.w));
            *reinterpret_cast<float4*>(out0 + gi) = o;
            *reinterpret_cast<float4*>(&As[tok][k4]) = v;   // b128 write, no transpose
        }
        // ---- stage W tile (32 k x 64 dh)
#pragma unroll
        for (int r = 0; r < 4; ++r) {
            const int f = r * 128 + tid;
            const int row = f >> 4;
            const int col = (f & 15) * 4;
            *reinterpret_cast<float4*>(&Ws[row][col]) =
                *reinterpret_cast<const float4*>(w1 + (long long)(kBase + ko + row) * NDH + col);
        }
        __syncthreads();

#pragma unroll
        for (int kk = 0; kk < BK; kk += 4) {
            float4 av[8];
#pragma unroll
            for (int t = 0; t < 8; ++t)
                av[t] = *reinterpret_cast<const float4*>(&As[ty + 16 * t][kk]);
#pragma unroll
            for (int i = 0; i < 4; ++i) {
                const float4 w0 = *reinterpret_cast<const float4*>(&Ws[kk + i][tx * 8]);
                const float4 w1v = *reinterpret_cast<const float4*>(&Ws[kk + i][tx * 8 + 4]);
#pragma unroll
                for (int t = 0; t < 8; ++t) {
                    const float a = reinterpret_cast<const float*>(&av[t])[i];
                    acc[t][0] += a * w0.x;  acc[t][1] += a * w0.y;
                    acc[t][2] += a * w0.z;  acc[t][3] += a * w0.w;
                    acc[t][4] += a * w1v.x; acc[t][5] += a * w1v.y;
                    acc[t][6] += a * w1v.z; acc[t][7] += a * w1v.w;
                }
            }
        }
        __syncthreads();
    }

    // ---- write partial sums: part[kc][token][dh]
#pragma unroll
    for (int t = 0; t < 8; ++t) {
        const long long o =
            ((long long)kc * (NB * NS) + tokenBase + ty + 16 * t) * NDH + tx * 8;
        const float4 lo = make_float4(acc[t][0], acc[t][1], acc[t][2], acc[t][3]);
        const float4 hi = make_float4(acc[t][4], acc[t][5], acc[t][6], acc[t][7]);
        *reinterpret_cast<float4*>(part + o) = lo;
        *reinterpret_cast<float4*>(part + o + 4) = hi;
    }
}

// ---------------------------------------------------------------------------
// K1b: logits[T] = relu(sum_kc part + b1) . w2 + b2. One wave per token.
// ---------------------------------------------------------------------------
__global__ __launch_bounds__(256) void k_reduce(
    const float* __restrict__ part, const float* __restrict__ b1,
    const float* __restrict__ w2, const float* __restrict__ b2,
    float* __restrict__ logits)
{
    const int T = blockIdx.x * 4 + (threadIdx.x >> 6);
    const int lane = threadIdx.x & 63;
    float s = 0.0f;
#pragma unroll
    for (int kc = 0; kc < KS; ++kc)
        s += part[((long long)kc * (NB * NS) + T) * NDH + lane];
    const float h = fmaxf(s + b1[lane], 0.0f);
    float p = h * w2[lane];
#pragma unroll
    for (int m = 1; m < 64; m <<= 1) p += __shfl_xor(p, m, 64);
    if (lane == 0) logits[T] = p + b2[0];
}

// ---------------------------------------------------------------------------
// K2: per-batch gumbel top-k via exact 32-bit radix select + O(C^2) ranking
// (comparator: key desc, index asc — matches jax.lax.top_k), plus
// log_softmax gather mean. One block per batch, 1024 threads.
// ---------------------------------------------------------------------------
__global__ __launch_bounds__(1024) void k_topk(
    const float* __restrict__ logits, const float* __restrict__ noise,
    float* __restrict__ outIdx, float* __restrict__ outType,
    float* __restrict__ outLP, int* __restrict__ wsIdx)
{
    __shared__ unsigned int ukey[NS];
    __shared__ float rawl[NS];
    __shared__ unsigned int hist[256];
    __shared__ unsigned int sufx[256];
    __shared__ float red[1024];
    __shared__ unsigned int candU[512];
    __shared__ int candIdx[512];
    __shared__ int sel[NK];
    __shared__ unsigned int misc[3];   // 0: prefix, 1: rem, 2: candCount

    const int b = blockIdx.x;
    const int tid = threadIdx.x;

    for (int e = tid; e < NS; e += 1024) {
        const float l = logits[b * NS + e];
        const float u = noise[b * NS + e];
        const float g = -logf(-logf(u));
        unsigned int x = __float_as_uint(l + g);
        x = (x & 0x80000000u) ? ~x : (x | 0x80000000u);   // monotonic uint map
        ukey[e] = x;
        rawl[e] = l;
    }
    if (tid == 0) { misc[0] = 0u; misc[1] = NK; misc[2] = 0u; }
    __syncthreads();

    // exact radix select: after 4 passes misc[0] = T (32-bit threshold key)
    for (int pass = 0; pass < 4; ++pass) {
        const int shift = 24 - pass * 8;
        if (tid < 256) hist[tid] = 0u;
        __syncthreads();
        const unsigned int pfx = misc[0];
        for (int e = tid; e < NS; e += 1024) {
            const unsigned int x = ukey[e];
            if (pass == 0 || (x >> (shift + 8)) == pfx)
                atomicAdd(&hist[(x >> shift) & 255u], 1u);
        }
        __syncthreads();
        if (tid < 256) sufx[tid] = hist[tid];
        __syncthreads();
        for (int off = 1; off < 256; off <<= 1) {   // suffix scan (Hillis-Steele)
            unsigned int v = 0u;
            if (tid < 256) v = sufx[tid] + ((tid + off < 256) ? sufx[tid + off] : 0u);
            __syncthreads();
            if (tid < 256) sufx[tid] = v;
            __syncthreads();
        }
        const unsigned int rem = misc[1];
        if (tid < 256) {
            const unsigned int ge = sufx[tid];
            const unsigned int gt = (tid < 255) ? sufx[tid + 1] : 0u;
            if (ge >= rem && gt < rem) {            // unique b*
                misc[0] = (pfx << 8) | (unsigned int)tid;
                misc[1] = rem - gt;
            }
        }
        __syncthreads();
    }

    const unsigned int T = misc[0];
    for (int e = tid; e < NS; e += 1024) {
        if (ukey[e] >= T) {
            const unsigned int slot = atomicAdd(&misc[2], 1u);
            if (slot < 512u) { candU[slot] = ukey[e]; candIdx[slot] = e; }
        }
    }
    __syncthreads();
    const int C = (int)min(misc[2], 512u);

    // exact rank per candidate (C ~ 256): rank < NK -> emit at slot rank
    for (int c = tid; c < C; c += 1024) {
        const unsigned int xu = candU[c];
        const int xi = candIdx[c];
        int r = 0;
        for (int j = 0; j < C; ++j) {
            const unsigned int yu = candU[j];
            r += (int)((yu > xu) || (yu == xu && candIdx[j] < xi));
        }
        if (r < NK) {
            outIdx[b * NK + r] = (float)xi;
            outType[b * NK + r] = 1.0f;   // FIXED_TYPE
            wsIdx[b * NK + r] = xi;
            sel[r] = xi;
        }
    }

    // log-softmax denominator over raw logits
    float lm = -INFINITY;
    for (int e = tid; e < NS; e += 1024) lm = fmaxf(lm, rawl[e]);
    red[tid] = lm;
    __syncthreads();
    for (int s2 = 512; s2 > 0; s2 >>= 1) {
        if (tid < s2) red[tid] = fmaxf(red[tid], red[tid + s2]);
        __syncthreads();
    }
    const float maxv = red[0];
    __syncthreads();
    float ls = 0.0f;
    for (int e = tid; e < NS; e += 1024) ls += expf(rawl[e] - maxv);
    red[tid] = ls;
    __syncthreads();
    for (int s2 = 512; s2 > 0; s2 >>= 1) {
        if (tid < s2) red[tid] += red[tid + s2];
        __syncthreads();
    }
    const float lse = logf(red[0]);
    __syncthreads();

    float contrib = (tid < NK) ? (rawl[sel[tid]] - maxv - lse) : 0.0f;
    red[tid] = contrib;
    __syncthreads();
    for (int s2 = 512; s2 > 0; s2 >>= 1) {
        if (tid < s2) red[tid] += red[tid + s2];
        __syncthreads();
    }
    if (tid == 0) outLP[b] = red[0] / (float)NK;
}

// ---------------------------------------------------------------------------
// K3: zero the selected rows of out0 (perturb value = TYPE_VALUES[1]*SCALE = 0)
// ---------------------------------------------------------------------------
__global__ __launch_bounds__(256) void k_zero_rows(
    const int* __restrict__ wsIdx, float* __restrict__ out0)
{
    const int blk = blockIdx.x;        // 0 .. NB*NK-1
    const int b = blk >> 8;
    const int r = blk & 255;
    const int row = wsIdx[b * NK + r];
    const float4 z = make_float4(0.f, 0.f, 0.f, 0.f);
    float4* p = reinterpret_cast<float4*>(out0 + ((long long)(b * NS + row)) * NH);
    p[threadIdx.x]       = z;
    p[threadIdx.x + 256] = z;
}

extern "C" void kernel_launch(void* const* d_in, const int* in_sizes, int n_in,
                              void* d_out, int out_size, void* d_ws, size_t ws_size,
                              hipStream_t stream) {
    const float* hs    = (const float*)d_in[0];   // (B,S,H) fp32
    const float* noise = (const float*)d_in[1];   // (B,S)   fp32
    const float* w1    = (const float*)d_in[2];   // (H,DH)
    const float* b1    = (const float*)d_in[3];   // (DH,)
    const float* w2    = (const float*)d_in[4];   // (DH,1)
    const float* b2    = (const float*)d_in[5];   // (1,)

    float* out0    = (float*)d_out;                       // (B,S,H) perturbed
    float* outIdx  = out0 + (long long)NB * NS * NH;      // (B,K) indices as float
    float* outType = outIdx + NB * NK;                    // (B,K) types as float
    float* outLP   = outType + NB * NK;                   // (B,)  log_prob

    float* logits = (float*)d_ws;                         // B*S floats
    int*   wsIdx  = (int*)d_ws + NB * NS;                 // B*K ints
    float* part   = (float*)d_ws + NB * NS + NB * NK;     // KS*B*S*DH floats (~33.5 MB)

    k_sel_gemm<<<256 * KS, 128, 0, stream>>>(hs, w1, out0, part);
    k_reduce<<<NB * NS / 4, 256, 0, stream>>>(part, b1, w2, b2, logits);
    k_topk<<<NB, 1024, 0, stream>>>(logits, noise, outIdx, outType, outLP, wsIdx);
    k_zero_rows<<<NB * NK, 256, 0, stream>>>(wsIdx, out0);
}